// Round 17
// baseline (73.635 us; speedup 1.0000x reference)
//
#include <hip/hip_runtime.h>

typedef unsigned short u16;
typedef unsigned int u32;
typedef __bf16 bf16x8 __attribute__((ext_vector_type(8)));
typedef float f32x16 __attribute__((ext_vector_type(16)));
typedef u32 u32x4 __attribute__((ext_vector_type(4)));

#define QSCALE 0.18033688011112042f  // 0.125 * log2(e): softmax temp folded into Q

__device__ __forceinline__ u16 bfbits(float f) {
  __bf16 h = (__bf16)f;  // RNE
  return __builtin_bit_cast(u16, h);
}
__device__ __forceinline__ u32 pack2(float lo, float hi) {
  return (u32)bfbits(lo) | ((u32)bfbits(hi) << 16);
}
// v_permlane32_swap_b32: a.hi-lanes := old b.lo-lanes; b.lo-lanes := old
// a.hi-lanes (HW-confirmed R7).
__device__ __forceinline__ void pl32swap(u32& a, u32& b) {
  asm volatile("v_permlane32_swap_b32 %0, %1" : "+v"(a), "+v"(b));
}
__device__ __forceinline__ void gload_lds16(const void* g, void* l) {
  __builtin_amdgcn_global_load_lds(
      (const __attribute__((address_space(1))) void*)g,
      (__attribute__((address_space(3))) void*)l, 16, 0, 0);
}

// ---------------------------------------------------------------------------
// K/V projection (R11-proven, ~8us). 512 blocks x 256 thr, 64 rows each.
// ---------------------------------------------------------------------------
__global__ __launch_bounds__(256) void kv_proj_kernel(
    const float* __restrict__ x,
    const float* __restrict__ Wk, const float* __restrict__ bk,
    const float* __restrict__ Wv, const float* __restrict__ bv,
    u16* __restrict__ Kb, u16* __restrict__ VbT) {
  __shared__ __align__(16) u16 xs[64 * 64];
  const int t = threadIdx.x, w = t >> 6, lane = t & 63;
  const int ql = lane & 31, hi = lane >> 5;
  const int ws_ = w & 1;
  const int th = w >> 1;
  const size_t rg0 = (size_t)blockIdx.x * 64;

  {
    const float4* xsrc = reinterpret_cast<const float4*>(x + rg0 * 64);
#pragma unroll
    for (int i = 0; i < 4; ++i) {
      int idx = t + i * 256;
      int row = idx >> 4, c4 = idx & 15;
      float4 v = xsrc[idx];
      char* p = reinterpret_cast<char*>(xs) + row * 128 + ((c4 * 8) ^ ((row & 7) << 4));
      *reinterpret_cast<uint2*>(p) = make_uint2(pack2(v.x, v.y), pack2(v.z, v.w));
    }
  }
  __syncthreads();

  bf16x8 xf[4];
  {
    const int row = ws_ * 32 + ql;
    const char* base = reinterpret_cast<const char*>(xs) + row * 128;
    const int swz = (row & 7) << 4;
#pragma unroll
    for (int j = 0; j < 4; ++j)
      xf[j] = *reinterpret_cast<const bf16x8*>(base + ((j * 32 + hi * 16) ^ swz));
  }

  const float* W = th ? Wv : Wk;
  const float* bb = th ? bv : bk;
  const int b = (int)(rg0 >> 11);
  const int n0 = (int)(rg0 & 2047);

#pragma unroll
  for (int ct = 0; ct < 4; ++ct) {
    const int c = ct * 32 + ql;
    f32x16 acc;
#pragma unroll
    for (int i2 = 0; i2 < 16; ++i2) acc[i2] = 0.f;
#pragma unroll
    for (int j = 0; j < 4; ++j) {
      u32 wp[4];
#pragma unroll
      for (int e2 = 0; e2 < 4; ++e2) {
        float w0 = W[(j * 16 + hi * 8 + 2 * e2) * 128 + c];
        float w1 = W[(j * 16 + hi * 8 + 2 * e2 + 1) * 128 + c];
        wp[e2] = pack2(w0, w1);
      }
      u32x4 ww; ww.x = wp[0]; ww.y = wp[1]; ww.z = wp[2]; ww.w = wp[3];
      const bf16x8 wf = __builtin_bit_cast(bf16x8, ww);
      acc = __builtin_amdgcn_mfma_f32_32x32x16_bf16(xf[j], wf, acc, 0, 0, 0);
    }
    const float bias = bb[c];
    if (th == 0) {
#pragma unroll
      for (int reg = 0; reg < 16; ++reg) {
        const int i = (reg & 3) + 8 * (reg >> 2) + 4 * hi;
        Kb[(rg0 + ws_ * 32 + i) * 128 + c] = bfbits(fmaxf(acc[reg] + bias, 0.f));
      }
    } else {
      u16* vrow = VbT + ((size_t)(b * 128 + c)) * 2048;
#pragma unroll
      for (int g2 = 0; g2 < 4; ++g2) {
        u32 p0 = pack2(fmaxf(acc[4 * g2 + 0] + bias, 0.f),
                       fmaxf(acc[4 * g2 + 1] + bias, 0.f));
        u32 p1 = pack2(fmaxf(acc[4 * g2 + 2] + bias, 0.f),
                       fmaxf(acc[4 * g2 + 3] + bias, 0.f));
        const int n = n0 + ws_ * 32 + 8 * g2 + 4 * hi;
        *reinterpret_cast<uint2*>(vrow + n) = make_uint2(p0, p1);
      }
    }
  }
}

// ---------------------------------------------------------------------------
// Attention (R16 base). Single change: QK accumulator split into two
// independent dependency chains (s0a/s0b), summed at exp2 time.
// ---------------------------------------------------------------------------
__global__ __launch_bounds__(256) void attn_kernel(
    const float* __restrict__ x,
    const float* __restrict__ Wq, const float* __restrict__ bq,
    const u16* __restrict__ Kb, const u16* __restrict__ VbT,
    float* __restrict__ out) {
  __shared__ __align__(16) char smem[65536];

  const int bid = ((int)blockIdx.x & 7) * 64 + ((int)blockIdx.x >> 3);
  const int b = bid >> 5;
  const int qt = bid & 31;
  const int t = threadIdx.x, w = t >> 6, lane = t & 63;
  const int ql = lane & 31, hi = lane >> 5;
  const size_t rg0 = (size_t)b * 2048 + qt * 64;
  const int sw = (ql & 7) << 4;

  // ===== phase 0: Q projection into LDS =====
  {
    u16* xs = reinterpret_cast<u16*>(smem + 16384);  // [64][64] bf16 swz, 8KB
    const float4* xsrc = reinterpret_cast<const float4*>(x + rg0 * 64);
#pragma unroll
    for (int i = 0; i < 4; ++i) {
      int idx = t + i * 256;
      int row = idx >> 4, c4 = idx & 15;
      float4 v = xsrc[idx];
      char* p = reinterpret_cast<char*>(xs) + row * 128 + ((c4 * 8) ^ ((row & 7) << 4));
      *reinterpret_cast<uint2*>(p) = make_uint2(pack2(v.x, v.y), pack2(v.z, v.w));
    }
    __syncthreads();

    const int ws_ = w & 1;                 // row strip
    bf16x8 xf[4];
    {
      const int row = ws_ * 32 + ql;
      const char* base = reinterpret_cast<const char*>(xs) + row * 128;
      const int swz = (row & 7) << 4;
#pragma unroll
      for (int j = 0; j < 4; ++j)
        xf[j] = *reinterpret_cast<const bf16x8*>(base + ((j * 32 + hi * 16) ^ swz));
    }
#pragma unroll
    for (int u = 0; u < 2; ++u) {
      const int ct = (w >> 1) * 2 + u;
      const int c = ct * 32 + ql;
      f32x16 acc;
#pragma unroll
      for (int i2 = 0; i2 < 16; ++i2) acc[i2] = 0.f;
#pragma unroll
      for (int j = 0; j < 4; ++j) {
        u32 wp[4];
#pragma unroll
        for (int e2 = 0; e2 < 4; ++e2) {
          float w0 = Wq[(j * 16 + hi * 8 + 2 * e2) * 128 + c];
          float w1 = Wq[(j * 16 + hi * 8 + 2 * e2 + 1) * 128 + c];
          wp[e2] = pack2(w0, w1);
        }
        u32x4 ww; ww.x = wp[0]; ww.y = wp[1]; ww.z = wp[2]; ww.w = wp[3];
        const bf16x8 wf = __builtin_bit_cast(bf16x8, ww);
        acc = __builtin_amdgcn_mfma_f32_32x32x16_bf16(xf[j], wf, acc, 0, 0, 0);
      }
      const float bias = bq[c];
#pragma unroll
      for (int reg = 0; reg < 16; ++reg) {
        const int i = (reg & 3) + 8 * (reg >> 2) + 4 * hi;
        const int r = ws_ * 32 + i;
        *reinterpret_cast<u16*>(smem + r * 256 + ((2 * c) ^ ((r & 7) << 4))) =
            bfbits(fmaxf(acc[reg] + bias, 0.f) * QSCALE);
      }
    }
  }
  __syncthreads();   // Q tile complete in LDS[0..16KB)

  // ===== load Q fragments, then release LDS for staging =====
  const int qw = w >> 1, par = w & 1;
  const int q0 = qt * 64 + qw * 32;
  bf16x8 qf[8];
  {
    const int r = qw * 32 + ql;
    const char* base = smem + r * 256;
    const int swz = (r & 7) << 4;
#pragma unroll
    for (int f = 0; f < 8; ++f)
      qf[f] = *reinterpret_cast<const bf16x8*>(base + ((f * 32 + hi * 16) ^ swz));
  }
  __syncthreads();   // all qf reads done before DMA overwrites LDS

  // ===== attention body =====
  f32x16 Oacc[4], lacc;
#pragma unroll
  for (int i = 0; i < 16; ++i) {
    Oacc[0][i] = 0.f; Oacc[1][i] = 0.f; Oacc[2][i] = 0.f; Oacc[3][i] = 0.f;
    lacc[i] = 0.f;
  }
  u32x4 ow; ow.x = ow.y = ow.z = ow.w = 0x3F803F80u;
  const bf16x8 ones = __builtin_bit_cast(bf16x8, ow);

  const u16* Kbase = Kb + (size_t)b * 2048 * 128;
  const u16* Vbase = VbT + (size_t)b * 128 * 2048;

  const u16* kgp[4]; const u16* vgp[4];
  int ldso[4];
#pragma unroll
  for (int i = 0; i < 4; ++i) {
    const int Lb = (w * 4 + i) * 1024 + lane * 16;
    ldso[i] = (w * 4 + i) * 1024;
    const int kr = Lb >> 8;
    const int ks = ((Lb >> 4) & 15) ^ (kr & 7);
    kgp[i] = Kbase + kr * 128 + ks * 8;
    const int vr = Lb >> 7;
    const int vs = ((Lb >> 4) & 7) ^ (vr & 7);
    vgp[i] = Vbase + (size_t)vr * 2048 + vs * 8;
  }

  // hoisted per-lane LDS READ byte-offsets (superstep-invariant)
  int kread[8], vread[8];
#pragma unroll
  for (int f = 0; f < 8; ++f)
    kread[f] = (par * 32 + ql) * 256 + ((f * 32 + hi * 16) ^ sw);
#pragma unroll
  for (int s2 = 0; s2 < 2; ++s2)
#pragma unroll
    for (int dt = 0; dt < 4; ++dt) {
      const int dr = dt * 32 + ql;
      vread[s2 * 4 + dt] = dr * 128 + ((par * 64 + s2 * 32 + hi * 16) ^ ((dr & 7) << 4));
    }

#pragma unroll
  for (int i = 0; i < 4; ++i) {
    gload_lds16(kgp[i], smem + ldso[i]);
    gload_lds16(vgp[i], smem + 32768 + ldso[i]);
  }
  __syncthreads();

  for (int ss = 0; ss < 32; ++ss) {
    const int cur = ss & 1;
    if (ss < 31) {
      const size_t ko = (size_t)(ss + 1) * 8192;
      const int vo = (ss + 1) * 64;
      const int bo = (cur ^ 1) * 16384;
#pragma unroll
      for (int i = 0; i < 4; ++i) {
        gload_lds16(kgp[i] + ko, smem + bo + ldso[i]);
        gload_lds16(vgp[i] + vo, smem + 32768 + bo + ldso[i]);
      }
    }
    const char* kb0 = smem + cur * 16384;
    const char* vb0 = smem + 32768 + cur * 16384;

    // QK: two independent accumulate chains (halved dep latency)
    f32x16 s0a, s0b;
#pragma unroll
    for (int i = 0; i < 16; ++i) { s0a[i] = 0.f; s0b[i] = 0.f; }
    __builtin_amdgcn_s_setprio(1);
#pragma unroll
    for (int f2 = 0; f2 < 4; ++f2) {
      bf16x8 k0 = *reinterpret_cast<const bf16x8*>(kb0 + kread[2 * f2]);
      bf16x8 k1 = *reinterpret_cast<const bf16x8*>(kb0 + kread[2 * f2 + 1]);
      s0a = __builtin_amdgcn_mfma_f32_32x32x16_bf16(k0, qf[2 * f2], s0a, 0, 0, 0);
      s0b = __builtin_amdgcn_mfma_f32_32x32x16_bf16(k1, qf[2 * f2 + 1], s0b, 0, 0, 0);
    }
    __builtin_amdgcn_s_setprio(0);

    u32 pk[8];
#pragma unroll
    for (int m = 0; m < 8; ++m)
      pk[m] = pack2(__builtin_amdgcn_exp2f(s0a[2 * m] + s0b[2 * m]),
                    __builtin_amdgcn_exp2f(s0a[2 * m + 1] + s0b[2 * m + 1]));

    __builtin_amdgcn_s_setprio(1);
#pragma unroll
    for (int s2 = 0; s2 < 2; ++s2) {
      u32 X0 = pk[4 * s2 + 0], X1 = pk[4 * s2 + 1];
      u32 Y0 = pk[4 * s2 + 2], Y1 = pk[4 * s2 + 3];
      pl32swap(X0, Y0);
      pl32swap(X1, Y1);
      u32x4 frw; frw.x = X0; frw.y = X1; frw.z = Y0; frw.w = Y1;
      const bf16x8 pf = __builtin_bit_cast(bf16x8, frw);
      lacc = __builtin_amdgcn_mfma_f32_32x32x16_bf16(pf, ones, lacc, 0, 0, 0);
#pragma unroll
      for (int dt = 0; dt < 4; ++dt) {
        bf16x8 vf = *reinterpret_cast<const bf16x8*>(vb0 + vread[s2 * 4 + dt]);
        Oacc[dt] = __builtin_amdgcn_mfma_f32_32x32x16_bf16(pf, vf, Oacc[dt], 0, 0, 0);
      }
    }
    __builtin_amdgcn_s_setprio(0);

    __syncthreads();
  }

  // ---- combine kv-parity partials ----
  float* Ost = reinterpret_cast<float*>(smem);
  float* Lst = reinterpret_cast<float*>(smem + 32768);
  if (par == 1) {
#pragma unroll
    for (int reg = 0; reg < 16; ++reg) {
      const int qr = (reg & 3) + 8 * (reg >> 2) + 4 * hi;
      float* orow = Ost + (size_t)(qw * 32 + qr) * 128 + ql;
#pragma unroll
      for (int dt = 0; dt < 4; ++dt) orow[dt * 32] = Oacc[dt][reg];
      if (ql == 0) Lst[qw * 32 + qr] = lacc[reg];
    }
  }
  __syncthreads();
  if (par == 0) {
#pragma unroll
    for (int reg = 0; reg < 16; ++reg) {
      const int qr = (reg & 3) + 8 * (reg >> 2) + 4 * hi;
      const float inv = 1.f / (lacc[reg] + Lst[qw * 32 + qr]);
      const float* prow = Ost + (size_t)(qw * 32 + qr) * 128 + ql;
      float* orow = out + ((size_t)(b * 2048 + q0 + qr)) * 128 + ql;
#pragma unroll
      for (int dt = 0; dt < 4; ++dt)
        orow[dt * 32] = (Oacc[dt][reg] + prow[dt * 32]) * inv;
    }
  }
}

extern "C" void kernel_launch(void* const* d_in, const int* in_sizes, int n_in,
                              void* d_out, int out_size, void* d_ws, size_t ws_size,
                              hipStream_t stream) {
  const float* x  = (const float*)d_in[0];
  const float* Wq = (const float*)d_in[1];
  const float* bq = (const float*)d_in[2];
  const float* Wk = (const float*)d_in[3];
  const float* bk = (const float*)d_in[4];
  const float* Wv = (const float*)d_in[5];
  const float* bv = (const float*)d_in[6];
  float* out = (float*)d_out;

  u16* Kb  = (u16*)d_ws;                              // [B*N][128] bf16, 8 MB
  u16* VbT = Kb + (size_t)16 * 2048 * 128;            // [B][128][N] bf16, 8 MB

  kv_proj_kernel<<<512, 256, 0, stream>>>(x, Wk, bk, Wv, bv, Kb, VbT);
  attn_kernel<<<512, 256, 0, stream>>>(x, Wq, bq, Kb, VbT, out);
}

// Round 18
// 69.697 us; speedup vs baseline: 1.0565x; 1.0565x over previous
//
#include <hip/hip_runtime.h>

typedef unsigned short u16;
typedef unsigned int u32;
typedef __bf16 bf16x8 __attribute__((ext_vector_type(8)));
typedef float f32x16 __attribute__((ext_vector_type(16)));
typedef u32 u32x4 __attribute__((ext_vector_type(4)));

#define QSCALE 0.18033688011112042f  // 0.125 * log2(e): softmax temp folded into Q

__device__ __forceinline__ u16 bfbits(float f) {
  __bf16 h = (__bf16)f;  // RNE
  return __builtin_bit_cast(u16, h);
}
__device__ __forceinline__ u32 pack2(float lo, float hi) {
  return (u32)bfbits(lo) | ((u32)bfbits(hi) << 16);
}
// v_permlane32_swap_b32: a.hi-lanes := old b.lo-lanes; b.lo-lanes := old
// a.hi-lanes (HW-confirmed R7).
__device__ __forceinline__ void pl32swap(u32& a, u32& b) {
  asm volatile("v_permlane32_swap_b32 %0, %1" : "+v"(a), "+v"(b));
}
__device__ __forceinline__ void gload_lds16(const void* g, void* l) {
  __builtin_amdgcn_global_load_lds(
      (const __attribute__((address_space(1))) void*)g,
      (__attribute__((address_space(3))) void*)l, 16, 0, 0);
}

// ---------------------------------------------------------------------------
// K/V projection (R11-proven, ~8us). 512 blocks x 256 thr, 64 rows each.
// ---------------------------------------------------------------------------
__global__ __launch_bounds__(256) void kv_proj_kernel(
    const float* __restrict__ x,
    const float* __restrict__ Wk, const float* __restrict__ bk,
    const float* __restrict__ Wv, const float* __restrict__ bv,
    u16* __restrict__ Kb, u16* __restrict__ VbT) {
  __shared__ __align__(16) u16 xs[64 * 64];
  const int t = threadIdx.x, w = t >> 6, lane = t & 63;
  const int ql = lane & 31, hi = lane >> 5;
  const int ws_ = w & 1;
  const int th = w >> 1;
  const size_t rg0 = (size_t)blockIdx.x * 64;

  {
    const float4* xsrc = reinterpret_cast<const float4*>(x + rg0 * 64);
#pragma unroll
    for (int i = 0; i < 4; ++i) {
      int idx = t + i * 256;
      int row = idx >> 4, c4 = idx & 15;
      float4 v = xsrc[idx];
      char* p = reinterpret_cast<char*>(xs) + row * 128 + ((c4 * 8) ^ ((row & 7) << 4));
      *reinterpret_cast<uint2*>(p) = make_uint2(pack2(v.x, v.y), pack2(v.z, v.w));
    }
  }
  __syncthreads();

  bf16x8 xf[4];
  {
    const int row = ws_ * 32 + ql;
    const char* base = reinterpret_cast<const char*>(xs) + row * 128;
    const int swz = (row & 7) << 4;
#pragma unroll
    for (int j = 0; j < 4; ++j)
      xf[j] = *reinterpret_cast<const bf16x8*>(base + ((j * 32 + hi * 16) ^ swz));
  }

  const float* W = th ? Wv : Wk;
  const float* bb = th ? bv : bk;
  const int b = (int)(rg0 >> 11);
  const int n0 = (int)(rg0 & 2047);

#pragma unroll
  for (int ct = 0; ct < 4; ++ct) {
    const int c = ct * 32 + ql;
    f32x16 acc;
#pragma unroll
    for (int i2 = 0; i2 < 16; ++i2) acc[i2] = 0.f;
#pragma unroll
    for (int j = 0; j < 4; ++j) {
      u32 wp[4];
#pragma unroll
      for (int e2 = 0; e2 < 4; ++e2) {
        float w0 = W[(j * 16 + hi * 8 + 2 * e2) * 128 + c];
        float w1 = W[(j * 16 + hi * 8 + 2 * e2 + 1) * 128 + c];
        wp[e2] = pack2(w0, w1);
      }
      u32x4 ww; ww.x = wp[0]; ww.y = wp[1]; ww.z = wp[2]; ww.w = wp[3];
      const bf16x8 wf = __builtin_bit_cast(bf16x8, ww);
      acc = __builtin_amdgcn_mfma_f32_32x32x16_bf16(xf[j], wf, acc, 0, 0, 0);
    }
    const float bias = bb[c];
    if (th == 0) {
#pragma unroll
      for (int reg = 0; reg < 16; ++reg) {
        const int i = (reg & 3) + 8 * (reg >> 2) + 4 * hi;
        Kb[(rg0 + ws_ * 32 + i) * 128 + c] = bfbits(fmaxf(acc[reg] + bias, 0.f));
      }
    } else {
      u16* vrow = VbT + ((size_t)(b * 128 + c)) * 2048;
#pragma unroll
      for (int g2 = 0; g2 < 4; ++g2) {
        u32 p0 = pack2(fmaxf(acc[4 * g2 + 0] + bias, 0.f),
                       fmaxf(acc[4 * g2 + 1] + bias, 0.f));
        u32 p1 = pack2(fmaxf(acc[4 * g2 + 2] + bias, 0.f),
                       fmaxf(acc[4 * g2 + 3] + bias, 0.f));
        const int n = n0 + ws_ * 32 + 8 * g2 + 4 * hi;
        *reinterpret_cast<uint2*>(vrow + n) = make_uint2(p0, p1);
      }
    }
  }
}

// ---------------------------------------------------------------------------
// Attention (R16-exact, best measured: attn 55.7us). In-kernel Q projection,
// K/V double-buffered global_load_lds DMA, one barrier per superstep,
// single-chain QK, setprio, hoisted LDS read offsets.
// ---------------------------------------------------------------------------
__global__ __launch_bounds__(256) void attn_kernel(
    const float* __restrict__ x,
    const float* __restrict__ Wq, const float* __restrict__ bq,
    const u16* __restrict__ Kb, const u16* __restrict__ VbT,
    float* __restrict__ out) {
  __shared__ __align__(16) char smem[65536];

  const int bid = ((int)blockIdx.x & 7) * 64 + ((int)blockIdx.x >> 3);
  const int b = bid >> 5;
  const int qt = bid & 31;
  const int t = threadIdx.x, w = t >> 6, lane = t & 63;
  const int ql = lane & 31, hi = lane >> 5;
  const size_t rg0 = (size_t)b * 2048 + qt * 64;
  const int sw = (ql & 7) << 4;

  // ===== phase 0: Q projection into LDS =====
  {
    u16* xs = reinterpret_cast<u16*>(smem + 16384);  // [64][64] bf16 swz, 8KB
    const float4* xsrc = reinterpret_cast<const float4*>(x + rg0 * 64);
#pragma unroll
    for (int i = 0; i < 4; ++i) {
      int idx = t + i * 256;
      int row = idx >> 4, c4 = idx & 15;
      float4 v = xsrc[idx];
      char* p = reinterpret_cast<char*>(xs) + row * 128 + ((c4 * 8) ^ ((row & 7) << 4));
      *reinterpret_cast<uint2*>(p) = make_uint2(pack2(v.x, v.y), pack2(v.z, v.w));
    }
    __syncthreads();

    const int ws_ = w & 1;                 // row strip
    bf16x8 xf[4];
    {
      const int row = ws_ * 32 + ql;
      const char* base = reinterpret_cast<const char*>(xs) + row * 128;
      const int swz = (row & 7) << 4;
#pragma unroll
      for (int j = 0; j < 4; ++j)
        xf[j] = *reinterpret_cast<const bf16x8*>(base + ((j * 32 + hi * 16) ^ swz));
    }
#pragma unroll
    for (int u = 0; u < 2; ++u) {
      const int ct = (w >> 1) * 2 + u;
      const int c = ct * 32 + ql;
      f32x16 acc;
#pragma unroll
      for (int i2 = 0; i2 < 16; ++i2) acc[i2] = 0.f;
#pragma unroll
      for (int j = 0; j < 4; ++j) {
        u32 wp[4];
#pragma unroll
        for (int e2 = 0; e2 < 4; ++e2) {
          float w0 = Wq[(j * 16 + hi * 8 + 2 * e2) * 128 + c];
          float w1 = Wq[(j * 16 + hi * 8 + 2 * e2 + 1) * 128 + c];
          wp[e2] = pack2(w0, w1);
        }
        u32x4 ww; ww.x = wp[0]; ww.y = wp[1]; ww.z = wp[2]; ww.w = wp[3];
        const bf16x8 wf = __builtin_bit_cast(bf16x8, ww);
        acc = __builtin_amdgcn_mfma_f32_32x32x16_bf16(xf[j], wf, acc, 0, 0, 0);
      }
      const float bias = bq[c];
#pragma unroll
      for (int reg = 0; reg < 16; ++reg) {
        const int i = (reg & 3) + 8 * (reg >> 2) + 4 * hi;
        const int r = ws_ * 32 + i;
        *reinterpret_cast<u16*>(smem + r * 256 + ((2 * c) ^ ((r & 7) << 4))) =
            bfbits(fmaxf(acc[reg] + bias, 0.f) * QSCALE);
      }
    }
  }
  __syncthreads();   // Q tile complete in LDS[0..16KB)

  // ===== load Q fragments, then release LDS for staging =====
  const int qw = w >> 1, par = w & 1;
  const int q0 = qt * 64 + qw * 32;
  bf16x8 qf[8];
  {
    const int r = qw * 32 + ql;
    const char* base = smem + r * 256;
    const int swz = (r & 7) << 4;
#pragma unroll
    for (int f = 0; f < 8; ++f)
      qf[f] = *reinterpret_cast<const bf16x8*>(base + ((f * 32 + hi * 16) ^ swz));
  }
  __syncthreads();   // all qf reads done before DMA overwrites LDS

  // ===== attention body =====
  f32x16 Oacc[4], lacc;
#pragma unroll
  for (int i = 0; i < 16; ++i) {
    Oacc[0][i] = 0.f; Oacc[1][i] = 0.f; Oacc[2][i] = 0.f; Oacc[3][i] = 0.f;
    lacc[i] = 0.f;
  }
  u32x4 ow; ow.x = ow.y = ow.z = ow.w = 0x3F803F80u;
  const bf16x8 ones = __builtin_bit_cast(bf16x8, ow);

  const u16* Kbase = Kb + (size_t)b * 2048 * 128;
  const u16* Vbase = VbT + (size_t)b * 128 * 2048;

  const u16* kgp[4]; const u16* vgp[4];
  int ldso[4];
#pragma unroll
  for (int i = 0; i < 4; ++i) {
    const int Lb = (w * 4 + i) * 1024 + lane * 16;
    ldso[i] = (w * 4 + i) * 1024;
    const int kr = Lb >> 8;
    const int ks = ((Lb >> 4) & 15) ^ (kr & 7);
    kgp[i] = Kbase + kr * 128 + ks * 8;
    const int vr = Lb >> 7;
    const int vs = ((Lb >> 4) & 7) ^ (vr & 7);
    vgp[i] = Vbase + (size_t)vr * 2048 + vs * 8;
  }

  // hoisted per-lane LDS READ byte-offsets (superstep-invariant)
  int kread[8], vread[8];
#pragma unroll
  for (int f = 0; f < 8; ++f)
    kread[f] = (par * 32 + ql) * 256 + ((f * 32 + hi * 16) ^ sw);
#pragma unroll
  for (int s2 = 0; s2 < 2; ++s2)
#pragma unroll
    for (int dt = 0; dt < 4; ++dt) {
      const int dr = dt * 32 + ql;
      vread[s2 * 4 + dt] = dr * 128 + ((par * 64 + s2 * 32 + hi * 16) ^ ((dr & 7) << 4));
    }

#pragma unroll
  for (int i = 0; i < 4; ++i) {
    gload_lds16(kgp[i], smem + ldso[i]);
    gload_lds16(vgp[i], smem + 32768 + ldso[i]);
  }
  __syncthreads();

  for (int ss = 0; ss < 32; ++ss) {
    const int cur = ss & 1;
    if (ss < 31) {
      const size_t ko = (size_t)(ss + 1) * 8192;
      const int vo = (ss + 1) * 64;
      const int bo = (cur ^ 1) * 16384;
#pragma unroll
      for (int i = 0; i < 4; ++i) {
        gload_lds16(kgp[i] + ko, smem + bo + ldso[i]);
        gload_lds16(vgp[i] + vo, smem + 32768 + bo + ldso[i]);
      }
    }
    const char* kb0 = smem + cur * 16384;
    const char* vb0 = smem + 32768 + cur * 16384;

    f32x16 s0;
#pragma unroll
    for (int i = 0; i < 16; ++i) s0[i] = 0.f;
    __builtin_amdgcn_s_setprio(1);
#pragma unroll
    for (int f = 0; f < 8; ++f) {
      bf16x8 k0 = *reinterpret_cast<const bf16x8*>(kb0 + kread[f]);
      s0 = __builtin_amdgcn_mfma_f32_32x32x16_bf16(k0, qf[f], s0, 0, 0, 0);
    }
    __builtin_amdgcn_s_setprio(0);

    u32 pk[8];
#pragma unroll
    for (int m = 0; m < 8; ++m)
      pk[m] = pack2(__builtin_amdgcn_exp2f(s0[2 * m]),
                    __builtin_amdgcn_exp2f(s0[2 * m + 1]));

    __builtin_amdgcn_s_setprio(1);
#pragma unroll
    for (int s2 = 0; s2 < 2; ++s2) {
      u32 X0 = pk[4 * s2 + 0], X1 = pk[4 * s2 + 1];
      u32 Y0 = pk[4 * s2 + 2], Y1 = pk[4 * s2 + 3];
      pl32swap(X0, Y0);
      pl32swap(X1, Y1);
      u32x4 frw; frw.x = X0; frw.y = X1; frw.z = Y0; frw.w = Y1;
      const bf16x8 pf = __builtin_bit_cast(bf16x8, frw);
      lacc = __builtin_amdgcn_mfma_f32_32x32x16_bf16(pf, ones, lacc, 0, 0, 0);
#pragma unroll
      for (int dt = 0; dt < 4; ++dt) {
        bf16x8 vf = *reinterpret_cast<const bf16x8*>(vb0 + vread[s2 * 4 + dt]);
        Oacc[dt] = __builtin_amdgcn_mfma_f32_32x32x16_bf16(pf, vf, Oacc[dt], 0, 0, 0);
      }
    }
    __builtin_amdgcn_s_setprio(0);

    __syncthreads();
  }

  // ---- combine kv-parity partials ----
  float* Ost = reinterpret_cast<float*>(smem);
  float* Lst = reinterpret_cast<float*>(smem + 32768);
  if (par == 1) {
#pragma unroll
    for (int reg = 0; reg < 16; ++reg) {
      const int qr = (reg & 3) + 8 * (reg >> 2) + 4 * hi;
      float* orow = Ost + (size_t)(qw * 32 + qr) * 128 + ql;
#pragma unroll
      for (int dt = 0; dt < 4; ++dt) orow[dt * 32] = Oacc[dt][reg];
      if (ql == 0) Lst[qw * 32 + qr] = lacc[reg];
    }
  }
  __syncthreads();
  if (par == 0) {
#pragma unroll
    for (int reg = 0; reg < 16; ++reg) {
      const int qr = (reg & 3) + 8 * (reg >> 2) + 4 * hi;
      const float inv = 1.f / (lacc[reg] + Lst[qw * 32 + qr]);
      const float* prow = Ost + (size_t)(qw * 32 + qr) * 128 + ql;
      float* orow = out + ((size_t)(b * 2048 + q0 + qr)) * 128 + ql;
#pragma unroll
      for (int dt = 0; dt < 4; ++dt)
        orow[dt * 32] = (Oacc[dt][reg] + prow[dt * 32]) * inv;
    }
  }
}

extern "C" void kernel_launch(void* const* d_in, const int* in_sizes, int n_in,
                              void* d_out, int out_size, void* d_ws, size_t ws_size,
                              hipStream_t stream) {
  const float* x  = (const float*)d_in[0];
  const float* Wq = (const float*)d_in[1];
  const float* bq = (const float*)d_in[2];
  const float* Wk = (const float*)d_in[3];
  const float* bk = (const float*)d_in[4];
  const float* Wv = (const float*)d_in[5];
  const float* bv = (const float*)d_in[6];
  float* out = (float*)d_out;

  u16* Kb  = (u16*)d_ws;                              // [B*N][128] bf16, 8 MB
  u16* VbT = Kb + (size_t)16 * 2048 * 128;            // [B][128][N] bf16, 8 MB

  kv_proj_kernel<<<512, 256, 0, stream>>>(x, Wk, bk, Wv, bv, Kb, VbT);
  attn_kernel<<<512, 256, 0, stream>>>(x, Wq, bq, Kb, VbT, out);
}